// Round 6
// baseline (165.924 us; speedup 1.0000x reference)
//
#include <hip/hip_runtime.h>
#include <hip/hip_bf16.h>
#include <math.h>

// BahdanauAttention: B=32, T=2048, D=512, U=512, fp32 in/out.
#define BB 32
#define TT 2048
#define DD 512
#define UU 512

typedef __attribute__((ext_vector_type(8))) short short8v;     // MFMA bf16 A/B frag
typedef __attribute__((ext_vector_type(4))) float floatx4;     // MFMA C/D frag
typedef __attribute__((ext_vector_type(8))) unsigned short ushort8v;

static __device__ inline unsigned short f2bf(float f) {
  __hip_bfloat16 h = __float2bfloat16(f);
  return *reinterpret_cast<unsigned short*>(&h);
}

static __device__ inline float bf2f(unsigned short u) {
  union { unsigned int i; float f; } x;
  x.i = ((unsigned int)u) << 16;
  return x.f;
}

static __device__ inline float fast_tanh(float x) {
  x = fminf(fmaxf(x, -15.f), 15.f);
  float e2 = __expf(2.f * x);
  return (e2 - 1.f) * __builtin_amdgcn_rcpf(e2 + 1.f);
}

// Raw 16B global->LDS copy. Global src is PER-LANE; LDS dest is
// wave-uniform base + lane*16 (pass base+tid*16, consistent per wave).
static __device__ inline void gload16(const void* g, void* l) {
  __builtin_amdgcn_global_load_lds(
      (const __attribute__((address_space(1))) unsigned int*)g,
      (__attribute__((address_space(3))) unsigned int*)(l), 16, 0, 0);
}

// ---------------------------------------------------------------------------
// K0a: values fp32 -> vbf bf16 row-major [B*T][D]. Pure streaming cvt.
// grid 2048, block 256; thread: 8 units of 8 floats.
// ---------------------------------------------------------------------------
__global__ __launch_bounds__(256) void pack_values_kernel(
    const float* __restrict__ values, unsigned short* __restrict__ vbf) {
  const size_t base = (size_t)blockIdx.x * 2048 + threadIdx.x;
  #pragma unroll
  for (int j = 0; j < 8; ++j) {
    const size_t g = base + (size_t)j * 256;   // 8-float unit index
    const float4* p = (const float4*)(values + g * 8);
    const float4 a = p[0], b = p[1];
    ushort8v o = {f2bf(a.x), f2bf(a.y), f2bf(a.z), f2bf(a.w),
                  f2bf(b.x), f2bf(b.y), f2bf(b.z), f2bf(b.w)};
    *(ushort8v*)(vbf + g * 8) = o;
  }
}

// ---------------------------------------------------------------------------
// K0b: W1[k][n] fp32 -> w1g blocked bf16: [ntile(4)][ktile(16)][kg(4)][col(128)][8]
// Each 8192B chunk (nt,kt) = byte image of the GEMM's B-LDS buffer.
// ---------------------------------------------------------------------------
__global__ __launch_bounds__(256) void pack_w1_kernel(
    const float* __restrict__ W1, unsigned short* __restrict__ w1g) {
  __shared__ float Wf[32][132];
  const int nt = blockIdx.x, kt = blockIdx.y;
  const int tid = threadIdx.x;
  {
    const int k = tid >> 3;
    const int n16 = (tid & 7) * 16;
    const float* src = W1 + (size_t)(kt * 32 + k) * UU + nt * 128 + n16;
    #pragma unroll
    for (int q = 0; q < 4; ++q) {
      const float4 v = *(const float4*)(src + q * 4);
      Wf[k][n16 + q * 4 + 0] = v.x;
      Wf[k][n16 + q * 4 + 1] = v.y;
      Wf[k][n16 + q * 4 + 2] = v.z;
      Wf[k][n16 + q * 4 + 3] = v.w;
    }
  }
  __syncthreads();
  unsigned short* dst = w1g + ((size_t)nt * 16 + kt) * 4096;  // 8192B chunk
  #pragma unroll
  for (int s = 0; s < 2; ++s) {
    const int idx = s * 256 + tid;   // 16B-chunk index 0..511
    const int kg = idx >> 7;
    const int col = idx & 127;
    ushort8v o;
    #pragma unroll
    for (int e = 0; e < 8; ++e) o[e] = f2bf(Wf[kg * 8 + e][col]);
    *(ushort8v*)(dst + idx * 8) = o;
  }
}

// ---------------------------------------------------------------------------
// K1: qb[b,u] = query[b,:] @ W2[:,u] + b2[u] + b1[u]
// ---------------------------------------------------------------------------
__global__ __launch_bounds__(256) void projq_kernel(
    const float* __restrict__ query, const float* __restrict__ W2,
    const float* __restrict__ b2, const float* __restrict__ b1,
    float* __restrict__ qb) {
  int b = blockIdx.x;
  int u = blockIdx.y * 256 + threadIdx.x;
  float acc = b2[u] + b1[u];
  const float* q = query + b * DD;
  #pragma unroll 8
  for (int d = 0; d < DD; ++d) acc += q[d] * W2[(size_t)d * UU + u];
  qb[b * UU + u] = acc;
}

// ---------------------------------------------------------------------------
// K2: MFMA score kernel — pure global_load_lds staging (m97 structure).
// 128x128 tile, BK=32, 4 waves (2x2, 64x64), 16 K-steps, LDS 16KB single-buf.
// A: vbf row-major, per-lane src (chunk c: row=c>>2, kslice=c&3), LDS [row][32].
// B: w1g blocked chunk, linear copy, LDS [kg][col][8].
// grid (4 n-tiles FAST, 512 m-tiles) -> A panel L3-reused across n-tiles.
// ---------------------------------------------------------------------------
#define BM 128
#define BN 128

__global__ __launch_bounds__(256) void score_kernel(
    const unsigned short* __restrict__ vbf, const unsigned short* __restrict__ w1g,
    const float* __restrict__ qb, const float* __restrict__ V,
    float* __restrict__ score) {
  __shared__ __align__(16) unsigned short As[BM][32];    // 8KB row-major
  __shared__ __align__(16) unsigned short Bs[4][BN][8];  // 8KB [kg][col][8]

  const int tid = threadIdx.x;
  const int n0 = blockIdx.x * BN;
  const int row0 = blockIdx.y * BM;
  const int b = row0 >> 11;           // row0 / TT
  const int lane = tid & 63;
  const int wid = tid >> 6;
  const int wr = (wid >> 1) * 64;
  const int wc = (wid & 1) * 64;
  const int fr = lane & 15;
  const int kg = lane >> 4;

  // A per-lane staging sources: chunk c0 = tid (row tid>>2, kslice tid&3),
  // chunk c1 = tid+256 (row 64 + tid>>2, same kslice).
  const unsigned short* a_src = vbf + (size_t)(row0 + (tid >> 2)) * DD + (tid & 3) * 8;
  char* asf = (char*)&As[0][0];

  const char* bchunk0 = (const char*)(w1g + (size_t)blockIdx.x * 16 * 4096);
  char* bsf = (char*)&Bs[0][0][0];

  floatx4 acc[4][4] = {};

  for (int kt = 0; kt < 16; ++kt) {
    // ---- stage A: 8KB, per-lane global src, linear LDS dest ----
    const unsigned short* ak = a_src + kt * 32;
    gload16(ak, asf + tid * 16);
    gload16(ak + 64 * DD, asf + 4096 + tid * 16);
    // ---- stage B: 8KB blocked chunk, linear copy ----
    const char* bsrc = bchunk0 + kt * 8192;
    gload16(bsrc + tid * 16, bsf + tid * 16);
    gload16(bsrc + 4096 + tid * 16, bsf + 4096 + tid * 16);
    __syncthreads();

    // ---- fragments + MFMA ----
    short8v af[4], bf[4];
    #pragma unroll
    for (int i = 0; i < 4; ++i)
      af[i] = *(const short8v*)&As[wr + i * 16 + fr][kg * 8];
    #pragma unroll
    for (int j = 0; j < 4; ++j)
      bf[j] = *(const short8v*)&Bs[kg][wc + j * 16 + fr][0];
    #pragma unroll
    for (int i = 0; i < 4; ++i)
      #pragma unroll
      for (int j = 0; j < 4; ++j)
        acc[i][j] = __builtin_amdgcn_mfma_f32_16x16x32_bf16(af[i], bf[j], acc[i][j], 0, 0, 0);
    __syncthreads();
  }

  // ---- epilogue: tanh + V-weighted reduce over u, then 16 col-lanes ----
  // C/D: col(u) = j*16 + fr, row = i*16 + kg*4 + reg   [verified r2-r5]
  float rowpart[4][4] = {};
  #pragma unroll
  for (int j = 0; j < 4; ++j) {
    const int u = n0 + wc + j * 16 + fr;
    const float qv = qb[b * UU + u];
    const float vv = V[u];
    #pragma unroll
    for (int i = 0; i < 4; ++i)
      #pragma unroll
      for (int reg = 0; reg < 4; ++reg)
        rowpart[i][reg] += fast_tanh(acc[i][j][reg] + qv) * vv;
  }
  #pragma unroll
  for (int i = 0; i < 4; ++i)
    #pragma unroll
    for (int reg = 0; reg < 4; ++reg) {
      float p = rowpart[i][reg];
      #pragma unroll
      for (int m = 1; m < 16; m <<= 1) p += __shfl_xor(p, m, 64);
      if (fr == 0)
        atomicAdd(&score[row0 + wr + i * 16 + kg * 4 + reg], p);
    }
}

// ---------------------------------------------------------------------------
// K3: softmax over T per batch.
// ---------------------------------------------------------------------------
__global__ __launch_bounds__(256) void softmax_kernel(
    const float* __restrict__ score, float* __restrict__ attn) {
  const int b = blockIdx.x;
  const int tid = threadIdx.x;
  __shared__ float red[256];

  float m = -INFINITY;
  for (int t = tid; t < TT; t += 256) m = fmaxf(m, score[b * TT + t]);
  red[tid] = m;
  __syncthreads();
  for (int s = 128; s > 0; s >>= 1) {
    if (tid < s) red[tid] = fmaxf(red[tid], red[tid + s]);
    __syncthreads();
  }
  const float bm = red[0];
  __syncthreads();

  float sum = 0.f;
  for (int t = tid; t < TT; t += 256) sum += __expf(score[b * TT + t] - bm);
  red[tid] = sum;
  __syncthreads();
  for (int s = 128; s > 0; s >>= 1) {
    if (tid < s) red[tid] += red[tid + s];
    __syncthreads();
  }
  const float inv = 1.f / red[0];
  __syncthreads();

  for (int t = tid; t < TT; t += 256)
    attn[b * TT + t] = __expf(score[b * TT + t] - bm) * inv;
}

// ---------------------------------------------------------------------------
// K4: context[b,d] = sum_t attn[b,t] * vbf[b,t,d]  (bf16 values, 16B loads)
// grid (SPLIT, B), block 256: 64 lanes cover 512 d (8 each); 4 row groups.
// ---------------------------------------------------------------------------
#define SPLIT 16
__global__ __launch_bounds__(256) void context_kernel(
    const unsigned short* __restrict__ vbf, const float* __restrict__ attn,
    float* __restrict__ ctx) {
  const int b = blockIdx.y;
  const int t0 = blockIdx.x * (TT / SPLIT);
  const int d = (threadIdx.x & 63) * 8;
  const int rg = threadIdx.x >> 6;  // 0..3
  float a[8] = {};
  for (int t = t0 + rg; t < t0 + TT / SPLIT; t += 4) {
    const float w = attn[b * TT + t];
    const ushort8v v = *(const ushort8v*)(vbf + (size_t)(b * TT + t) * DD + d);
    #pragma unroll
    for (int e = 0; e < 8; ++e) a[e] += w * bf2f(v[e]);
  }
  #pragma unroll
  for (int e = 0; e < 8; ++e) atomicAdd(&ctx[b * DD + d + e], a[e]);
}

// ---------------------------------------------------------------------------
extern "C" void kernel_launch(void* const* d_in, const int* in_sizes, int n_in,
                              void* d_out, int out_size, void* d_ws, size_t ws_size,
                              hipStream_t stream) {
  const float* query  = (const float*)d_in[0];
  const float* values = (const float*)d_in[1];
  const float* W1     = (const float*)d_in[2];
  const float* b1     = (const float*)d_in[3];
  const float* W2     = (const float*)d_in[4];
  const float* b2     = (const float*)d_in[5];
  const float* V      = (const float*)d_in[6];
  // d_in[7] = bV: uniform score shift -> softmax-invariant, dropped.

  float* ctx  = (float*)d_out;             // [B,D]
  float* attn = (float*)d_out + BB * DD;   // [B,T,1]

  // ws layout (all 16B-aligned): qb 64KB | score 256KB | w1g 512KB | vbf 64MB
  float* qb           = (float*)d_ws;                        // [B,U] fp32
  float* score        = qb + BB * UU;                        // [B*T] fp32
  unsigned short* w1g = (unsigned short*)(score + BB * TT);  // 512KB blocked bf16
  unsigned short* vbf = w1g + (size_t)UU * DD;               // [B*T][D] bf16, 64MB

  hipMemsetAsync(ctx, 0, BB * DD * sizeof(float), stream);
  hipMemsetAsync(score, 0, (size_t)BB * TT * sizeof(float), stream);

  pack_values_kernel<<<2048, 256, 0, stream>>>(values, vbf);
  pack_w1_kernel<<<dim3(4, 16), 256, 0, stream>>>(W1, w1g);
  projq_kernel<<<dim3(BB, UU / 256), 256, 0, stream>>>(query, W2, b2, b1, qb);

  // grid: x = n-tiles (4, fast -> L3 reuse of A panel), y = m-tiles (512)
  score_kernel<<<dim3(UU / BN, (BB * TT) / BM), 256, 0, stream>>>(
      vbf, w1g, qb, V, score);

  softmax_kernel<<<BB, 256, 0, stream>>>(score, attn);

  context_kernel<<<dim3(SPLIT, BB), 256, 0, stream>>>(vbf, attn, ctx);
}

// Round 7
// 114.967 us; speedup vs baseline: 1.4432x; 1.4432x over previous
//
#include <hip/hip_runtime.h>
#include <hip/hip_bf16.h>
#include <math.h>

// BahdanauAttention: B=32, T=2048, D=512, U=512, fp32 in/out.
#define BB 32
#define TT 2048
#define DD 512
#define UU 512

typedef __attribute__((ext_vector_type(8))) short short8v;     // MFMA bf16 A/B frag
typedef __attribute__((ext_vector_type(4))) float floatx4;     // MFMA C/D frag
typedef __attribute__((ext_vector_type(8))) unsigned short ushort8v;
typedef __attribute__((ext_vector_type(4))) unsigned short ushort4v;

static __device__ inline unsigned short f2bf(float f) {
  __hip_bfloat16 h = __float2bfloat16(f);
  return *reinterpret_cast<unsigned short*>(&h);
}

static __device__ inline float fast_tanh(float x) {
  x = fminf(fmaxf(x, -15.f), 15.f);
  float e2 = __expf(2.f * x);
  return (e2 - 1.f) * __builtin_amdgcn_rcpf(e2 + 1.f);
}

// Raw 16B global->LDS copy (per-lane global src; LDS dest = uniform base + lane*16).
static __device__ inline void gload16(const void* g, void* l) {
  __builtin_amdgcn_global_load_lds(
      (const __attribute__((address_space(1))) unsigned int*)g,
      (__attribute__((address_space(3))) unsigned int*)(l), 16, 0, 0);
}

// ---------------------------------------------------------------------------
// K0: W1[k][u] fp32 -> w1a blocked bf16 [kt(16)][kg(4)][u(512)][8]:
// w1a chunk (kt,kg,u)[e] = bf16(W1[kt*32+kg*8+e][u]) — the exact byte image
// of the score kernel's A-LDS buffer for K-step kt. grid 16, block 256.
// ---------------------------------------------------------------------------
__global__ __launch_bounds__(256) void pack_w1a_kernel(
    const float* __restrict__ W1, unsigned short* __restrict__ w1a) {
  __shared__ float Wf[32][516];  // 66 KB; pitch 516 -> col-gather conflict-free
  const int kt = blockIdx.x;
  const int tid = threadIdx.x;
  // load 32 x 512 fp32 slice, coalesced float4
  #pragma unroll
  for (int q = 0; q < 16; ++q) {
    const int flat = q * 256 + tid;        // float4 index
    const int row = flat >> 7;             // 128 float4 per row
    const int c4 = (flat & 127) * 4;
    const float4 v = *(const float4*)(W1 + (size_t)(kt * 32 + row) * UU + c4);
    Wf[row][c4 + 0] = v.x; Wf[row][c4 + 1] = v.y;
    Wf[row][c4 + 2] = v.z; Wf[row][c4 + 3] = v.w;
  }
  __syncthreads();
  unsigned short* dst = w1a + (size_t)kt * 16384;  // 32 KB per kt
  #pragma unroll
  for (int s = 0; s < 8; ++s) {
    const int c = s * 256 + tid;           // 16B-chunk index 0..2047
    const int kg = c >> 9;
    const int u = c & 511;
    ushort8v o;
    #pragma unroll
    for (int e = 0; e < 8; ++e) o[e] = f2bf(Wf[kg * 8 + e][u]);
    *(ushort8v*)(dst + c * 8) = o;
  }
}

// ---------------------------------------------------------------------------
// K1: qb[b,u] = query[b,:] @ W2[:,u] + b2[u] + b1[u]
// ---------------------------------------------------------------------------
__global__ __launch_bounds__(256) void projq_kernel(
    const float* __restrict__ query, const float* __restrict__ W2,
    const float* __restrict__ b2, const float* __restrict__ b1,
    float* __restrict__ qb) {
  int b = blockIdx.x;
  int u = blockIdx.y * 256 + threadIdx.x;
  float acc = b2[u] + b1[u];
  const float* q = query + b * DD;
  #pragma unroll 8
  for (int d = 0; d < DD; ++d) acc += q[d] * W2[(size_t)d * UU + u];
  qb[b * UU + u] = acc;
}

// ---------------------------------------------------------------------------
// K2: swapped-operand MFMA score kernel.
// A = W1 (u-dim, from w1a via global_load_lds, L2-hot 512 KB),
// B = values rows (fp32->bf16 reg-staged, read ONCE from HBM).
// Block: 64 rows x all 512 u; 8 waves; wave = 64u x 64m; BK=32, 16 steps.
// C[u][m]: col=lane&15 -> m, row=kg*4+reg -> u => u-reduce is in-register +
// 2 shfl + LDS cross-wave sum. No atomics; score written directly.
// LDS 42 KB single-buffer; __launch_bounds__(512,4) -> VGPR<=128, 2 blocks/CU.
// ---------------------------------------------------------------------------
#define SBM 64

__global__ __launch_bounds__(512, 4) void score_kernel(
    const float* __restrict__ values, const unsigned short* __restrict__ w1a,
    const float* __restrict__ qb, const float* __restrict__ V,
    float* __restrict__ score) {
  __shared__ __align__(16) unsigned short Aa[4][512][8];  // 32 KB [kg][u][8]
  __shared__ __align__(16) unsigned short Bs[4][SBM][8];  // 4 KB  [kg][m][8]
  __shared__ float qv_lds[512];
  __shared__ float vv_lds[512];
  __shared__ float part[8][SBM];

  const int tid = threadIdx.x;
  const int row0 = blockIdx.x * SBM;
  const int b = row0 >> 11;           // row0 / TT
  const int lane = tid & 63;
  const int wid = tid >> 6;           // 8 waves -> u slice
  const int wu = wid * 64;
  const int fr = lane & 15;
  const int kg = lane >> 4;

  // preload qb (b1,b2 folded) and V
  qv_lds[tid] = qb[b * UU + tid];
  vv_lds[tid] = V[tid];

  // B staging coords: thread -> (row sm, k-quad sj)
  const int sm = tid >> 3;
  const int sj = tid & 7;
  const float* bsrc = values + (size_t)(row0 + sm) * DD + sj * 4;
  unsigned short* bdst = &Bs[sj >> 1][sm][(sj & 1) * 4];

  const char* abase = (const char*)w1a;
  char* alds = (char*)&Aa[0][0][0];

  floatx4 acc[4][4] = {};  // [ju][jm]

  for (int kt = 0; kt < 16; ++kt) {
    // ---- B global load first (HBM latency starts ticking) ----
    const float4 bf4 = *(const float4*)(bsrc + kt * 32);
    // ---- A: 32 KB via global_load_lds (L2-hot, linear, coalesced) ----
    const char* ak = abase + kt * 32768;
    #pragma unroll
    for (int s = 0; s < 4; ++s) {
      const int c = s * 512 + tid;
      gload16(ak + c * 16, alds + c * 16);
    }
    // ---- B cvt + 8B LDS write ----
    {
      ushort4v q4 = {f2bf(bf4.x), f2bf(bf4.y), f2bf(bf4.z), f2bf(bf4.w)};
      *(ushort4v*)bdst = q4;
    }
    __syncthreads();

    // ---- fragments + MFMA (16 per wave per step) ----
    short8v af[4];
    #pragma unroll
    for (int ju = 0; ju < 4; ++ju)
      af[ju] = *(const short8v*)&Aa[kg][wu + ju * 16 + fr][0];
    #pragma unroll
    for (int jm = 0; jm < 4; ++jm) {
      const short8v bf = *(const short8v*)&Bs[kg][jm * 16 + fr][0];
      #pragma unroll
      for (int ju = 0; ju < 4; ++ju)
        acc[ju][jm] = __builtin_amdgcn_mfma_f32_16x16x32_bf16(af[ju], bf, acc[ju][jm], 0, 0, 0);
    }
    __syncthreads();
  }

  // ---- epilogue: tanh + V-weight; u lives on the register axis ----
  // C[u][m]: m = jm*16 + fr, u = wu + ju*16 + kg*4 + reg
  float pm[4] = {0.f, 0.f, 0.f, 0.f};
  #pragma unroll
  for (int ju = 0; ju < 4; ++ju) {
    const float4 qv = *(const float4*)&qv_lds[wu + ju * 16 + kg * 4];
    const float4 vv = *(const float4*)&vv_lds[wu + ju * 16 + kg * 4];
    const float qa[4] = {qv.x, qv.y, qv.z, qv.w};
    const float va[4] = {vv.x, vv.y, vv.z, vv.w};
    #pragma unroll
    for (int jm = 0; jm < 4; ++jm)
      #pragma unroll
      for (int reg = 0; reg < 4; ++reg)
        pm[jm] += fast_tanh(acc[ju][jm][reg] + qa[reg]) * va[reg];
  }
  // reduce over kg lane-groups (u), 2 hops
  #pragma unroll
  for (int jm = 0; jm < 4; ++jm) {
    pm[jm] += __shfl_xor(pm[jm], 16, 64);
    pm[jm] += __shfl_xor(pm[jm], 32, 64);
  }
  if (lane < 16) {
    #pragma unroll
    for (int jm = 0; jm < 4; ++jm) part[wid][jm * 16 + lane] = pm[jm];
  }
  __syncthreads();
  if (tid < SBM) {
    float s = 0.f;
    #pragma unroll
    for (int w = 0; w < 8; ++w) s += part[w][tid];
    score[row0 + tid] = s;
  }
}

// ---------------------------------------------------------------------------
// K3: softmax over T per batch.
// ---------------------------------------------------------------------------
__global__ __launch_bounds__(256) void softmax_kernel(
    const float* __restrict__ score, float* __restrict__ attn) {
  const int b = blockIdx.x;
  const int tid = threadIdx.x;
  __shared__ float red[256];

  float m = -INFINITY;
  for (int t = tid; t < TT; t += 256) m = fmaxf(m, score[b * TT + t]);
  red[tid] = m;
  __syncthreads();
  for (int s = 128; s > 0; s >>= 1) {
    if (tid < s) red[tid] = fmaxf(red[tid], red[tid + s]);
    __syncthreads();
  }
  const float bm = red[0];
  __syncthreads();

  float sum = 0.f;
  for (int t = tid; t < TT; t += 256) sum += __expf(score[b * TT + t] - bm);
  red[tid] = sum;
  __syncthreads();
  for (int s = 128; s > 0; s >>= 1) {
    if (tid < s) red[tid] += red[tid + s];
    __syncthreads();
  }
  const float inv = 1.f / red[0];
  __syncthreads();

  for (int t = tid; t < TT; t += 256)
    attn[b * TT + t] = __expf(score[b * TT + t] - bm) * inv;
}

// ---------------------------------------------------------------------------
// K4: context[b,d] = sum_t attn[b,t] * values[b,t,d]  (fp32, float4)
// ---------------------------------------------------------------------------
#define SPLIT 16
__global__ __launch_bounds__(256) void context_kernel(
    const float* __restrict__ values, const float* __restrict__ attn,
    float* __restrict__ ctx) {
  const int b = blockIdx.y;
  const int t0 = blockIdx.x * (TT / SPLIT);
  const int d = (threadIdx.x & 127) * 4;
  const int rg = threadIdx.x >> 7;
  float4 a = {0.f, 0.f, 0.f, 0.f};
  for (int t = t0 + rg; t < t0 + TT / SPLIT; t += 2) {
    const float w = attn[b * TT + t];
    const float4 v = *(const float4*)(values + (size_t)(b * TT + t) * DD + d);
    a.x += w * v.x; a.y += w * v.y; a.z += w * v.z; a.w += w * v.w;
  }
  atomicAdd(&ctx[b * DD + d + 0], a.x);
  atomicAdd(&ctx[b * DD + d + 1], a.y);
  atomicAdd(&ctx[b * DD + d + 2], a.z);
  atomicAdd(&ctx[b * DD + d + 3], a.w);
}

// ---------------------------------------------------------------------------
extern "C" void kernel_launch(void* const* d_in, const int* in_sizes, int n_in,
                              void* d_out, int out_size, void* d_ws, size_t ws_size,
                              hipStream_t stream) {
  const float* query  = (const float*)d_in[0];
  const float* values = (const float*)d_in[1];
  const float* W1     = (const float*)d_in[2];
  const float* b1     = (const float*)d_in[3];
  const float* W2     = (const float*)d_in[4];
  const float* b2     = (const float*)d_in[5];
  const float* V      = (const float*)d_in[6];
  // d_in[7] = bV: uniform score shift -> softmax-invariant, dropped.

  float* ctx  = (float*)d_out;             // [B,D]
  float* attn = (float*)d_out + BB * DD;   // [B,T,1]

  // ws: qb 64KB | score 256KB | w1a 512KB
  float* qb           = (float*)d_ws;                        // [B,U] fp32
  float* score        = qb + BB * UU;                        // [B*T] fp32
  unsigned short* w1a = (unsigned short*)(score + BB * TT);  // 512KB blocked bf16

  hipMemsetAsync(ctx, 0, BB * DD * sizeof(float), stream);  // context atomics

  pack_w1a_kernel<<<16, 256, 0, stream>>>(W1, w1a);
  projq_kernel<<<dim3(BB, UU / 256), 256, 0, stream>>>(query, W2, b2, b1, qb);

  score_kernel<<<(BB * TT) / SBM, 512, 0, stream>>>(values, w1a, qb, V, score);

  softmax_kernel<<<BB, 256, 0, stream>>>(score, attn);

  context_kernel<<<dim3(SPLIT, BB), 256, 0, stream>>>(values, attn, ctx);
}

// Round 9
// 112.007 us; speedup vs baseline: 1.4814x; 1.0264x over previous
//
#include <hip/hip_runtime.h>
#include <hip/hip_bf16.h>
#include <math.h>

// BahdanauAttention: B=32, T=2048, D=512, U=512, fp32 in/out.
#define BB 32
#define TT 2048
#define DD 512
#define UU 512

typedef __attribute__((ext_vector_type(8))) short short8v;     // MFMA bf16 A/B frag
typedef __attribute__((ext_vector_type(4))) float floatx4;     // MFMA C/D frag
typedef __attribute__((ext_vector_type(8))) unsigned short ushort8v;
typedef __attribute__((ext_vector_type(4))) unsigned short ushort4v;

static __device__ inline unsigned short f2bf(float f) {
  __hip_bfloat16 h = __float2bfloat16(f);
  return *reinterpret_cast<unsigned short*>(&h);
}

static __device__ inline float fast_tanh(float x) {
  x = fminf(fmaxf(x, -15.f), 15.f);
  float e2 = __expf(2.f * x);
  return (e2 - 1.f) * __builtin_amdgcn_rcpf(e2 + 1.f);
}

// ---------------------------------------------------------------------------
// K0: W1[k][u] fp32 -> w1a blocked bf16 [kt(16)][kg(4)][u(512)][8]:
// chunk (kt,kg,u)[e] = bf16(W1[kt*32+kg*8+e][u]).
// A wave's fragment load from this layout is 4 x 256B contiguous segments.
// ---------------------------------------------------------------------------
__global__ __launch_bounds__(256) void pack_w1a_kernel(
    const float* __restrict__ W1, unsigned short* __restrict__ w1a) {
  __shared__ float Wf[32][516];  // pitch 516 -> col-gather conflict-free
  const int kt = blockIdx.x;
  const int tid = threadIdx.x;
  #pragma unroll
  for (int q = 0; q < 16; ++q) {
    const int flat = q * 256 + tid;        // float4 index
    const int row = flat >> 7;
    const int c4 = (flat & 127) * 4;
    const float4 v = *(const float4*)(W1 + (size_t)(kt * 32 + row) * UU + c4);
    Wf[row][c4 + 0] = v.x; Wf[row][c4 + 1] = v.y;
    Wf[row][c4 + 2] = v.z; Wf[row][c4 + 3] = v.w;
  }
  __syncthreads();
  unsigned short* dst = w1a + (size_t)kt * 16384;  // 32 KB per kt
  #pragma unroll
  for (int s = 0; s < 8; ++s) {
    const int c = s * 256 + tid;           // 16B-chunk index 0..2047
    const int kg = c >> 9;
    const int u = c & 511;
    ushort8v o;
    #pragma unroll
    for (int e = 0; e < 8; ++e) o[e] = f2bf(Wf[kg * 8 + e][u]);
    *(ushort8v*)(dst + c * 8) = o;
  }
}

// ---------------------------------------------------------------------------
// K1: qb[b,u] = query[b,:] @ W2[:,u] + b2[u] + b1[u]
// ---------------------------------------------------------------------------
__global__ __launch_bounds__(256) void projq_kernel(
    const float* __restrict__ query, const float* __restrict__ W2,
    const float* __restrict__ b2, const float* __restrict__ b1,
    float* __restrict__ qb) {
  int b = blockIdx.x;
  int u = blockIdx.y * 256 + threadIdx.x;
  float acc = b2[u] + b1[u];
  const float* q = query + b * DD;
  #pragma unroll 8
  for (int d = 0; d < DD; ++d) acc += q[d] * W2[(size_t)d * UU + u];
  qb[b * UU + u] = acc;
}

// ---------------------------------------------------------------------------
// K2: swapped-operand MFMA score kernel, race-free pipeline.
// A = W1 (per-wave-private!): direct global->VGPR from L2-hot w1a,
//     register-double-buffered one K-step ahead (no LDS, no barriers for A).
// B = values rows (HBM, read once): reg-staged fp32->bf16, LDS double-buffer
//     2x4KB, T14 late-write (load at iter top, ds_write after MFMA phase).
// One __syncthreads per K-step (full-drain semantics, no manual waitcnts).
// 8 waves; wave = 64u x 64m. LDS ~14 KB.
// ---------------------------------------------------------------------------
#define SBM 64

__global__ __launch_bounds__(512, 4) void score_kernel(
    const float* __restrict__ values, const unsigned short* __restrict__ w1a,
    const float* __restrict__ qb, const float* __restrict__ V,
    float* __restrict__ score) {
  __shared__ __align__(16) unsigned short Bs[2][4][SBM][8];  // 2 x 4 KB bf16 [kg][m][8]
  __shared__ float qv_lds[512];
  __shared__ float vv_lds[512];
  __shared__ float part[8][SBM];

  const int tid = threadIdx.x;
  const int row0 = blockIdx.x * SBM;
  const int b = row0 >> 11;           // row0 / TT
  const int lane = tid & 63;
  const int wid = tid >> 6;           // 8 waves -> u slice
  const int wu = wid * 64;
  const int fr = lane & 15;
  const int kg = lane >> 4;

  qv_lds[tid] = qb[b * UU + tid];     // b1,b2 folded into qb
  vv_lds[tid] = V[tid];

  // B staging coords: thread -> (row sm, k-quad sj); 16B fp32 load, 8B bf16 write
  const int sm = tid >> 3;
  const int sj = tid & 7;
  const float* bsrc = values + (size_t)(row0 + sm) * DD + sj * 4;
  const int bofs = (sj >> 1) * (SBM * 8) + sm * 8 + (sj & 1) * 4;  // ushort ofs in one buffer

  // A-frag per-lane chunk offset (ushorts): (kg*512 + wu + ju*16 + fr) * 8
  const size_t aofs = (size_t)(kg * 512 + wu + fr) * 8;

  floatx4 acc[4][4] = {};  // [ju][jm]
  short8v af[2][4];
  float4 br;

  // ---- prologue: B(0) load + cvt + write; A(0) frags ----
  br = *(const float4*)(bsrc);
  #pragma unroll
  for (int ju = 0; ju < 4; ++ju)
    af[0][ju] = *(const short8v*)(w1a + aofs + (size_t)ju * 128);
  {
    ushort4v q4 = {f2bf(br.x), f2bf(br.y), f2bf(br.z), f2bf(br.w)};
    *(ushort4v*)((unsigned short*)&Bs[0][0][0][0] + bofs) = q4;
  }
  __syncthreads();

  // ---- main loop: one barrier per K-step ----
  #pragma unroll
  for (int t = 0; t < 16; ++t) {
    const int cur = t & 1;
    const int nxt = cur ^ 1;

    if (t < 15) {
      // issue next B row-slice load (HBM) and next A frags (L2) early
      br = *(const float4*)(bsrc + (size_t)(t + 1) * 32);
      #pragma unroll
      for (int ju = 0; ju < 4; ++ju)
        af[nxt][ju] = *(const short8v*)(w1a + (size_t)(t + 1) * 16384 + aofs + (size_t)ju * 128);
    }

    // ---- compute current: 16 MFMA/wave ----
    #pragma unroll
    for (int jm = 0; jm < 4; ++jm) {
      const short8v bfv = *(const short8v*)&Bs[cur][kg][jm * 16 + fr][0];
      #pragma unroll
      for (int ju = 0; ju < 4; ++ju)
        acc[ju][jm] = __builtin_amdgcn_mfma_f32_16x16x32_bf16(af[cur][ju], bfv, acc[ju][jm], 0, 0, 0);
    }

    if (t < 15) {
      // T14 late-write: cvt + ds_write B(t+1) after the MFMA phase
      ushort4v q4 = {f2bf(br.x), f2bf(br.y), f2bf(br.z), f2bf(br.w)};
      *(ushort4v*)((unsigned short*)&Bs[nxt][0][0][0] + bofs) = q4;
      __syncthreads();
    }
  }

  // ---- epilogue: tanh + V-weight; u on the register axis ----
  // C[u][m]: m = jm*16 + fr, u = wu + ju*16 + kg*4 + reg
  float pm[4] = {0.f, 0.f, 0.f, 0.f};
  #pragma unroll
  for (int ju = 0; ju < 4; ++ju) {
    const float4 qv = *(const float4*)&qv_lds[wu + ju * 16 + kg * 4];
    const float4 vv = *(const float4*)&vv_lds[wu + ju * 16 + kg * 4];
    const float qa[4] = {qv.x, qv.y, qv.z, qv.w};
    const float va[4] = {vv.x, vv.y, vv.z, vv.w};
    #pragma unroll
    for (int jm = 0; jm < 4; ++jm)
      #pragma unroll
      for (int reg = 0; reg < 4; ++reg)
        pm[jm] += fast_tanh(acc[ju][jm][reg] + qa[reg]) * va[reg];
  }
  #pragma unroll
  for (int jm = 0; jm < 4; ++jm) {
    pm[jm] += __shfl_xor(pm[jm], 16, 64);
    pm[jm] += __shfl_xor(pm[jm], 32, 64);
  }
  if (lane < 16) {
    #pragma unroll
    for (int jm = 0; jm < 4; ++jm) part[wid][jm * 16 + lane] = pm[jm];
  }
  __syncthreads();
  if (tid < SBM) {
    float s = 0.f;
    #pragma unroll
    for (int w = 0; w < 8; ++w) s += part[w][tid];
    score[row0 + tid] = s;
  }
}

// ---------------------------------------------------------------------------
// K3: softmax over T per batch.
// ---------------------------------------------------------------------------
__global__ __launch_bounds__(256) void softmax_kernel(
    const float* __restrict__ score, float* __restrict__ attn) {
  const int b = blockIdx.x;
  const int tid = threadIdx.x;
  __shared__ float red[256];

  float m = -INFINITY;
  for (int t = tid; t < TT; t += 256) m = fmaxf(m, score[b * TT + t]);
  red[tid] = m;
  __syncthreads();
  for (int s = 128; s > 0; s >>= 1) {
    if (tid < s) red[tid] = fmaxf(red[tid], red[tid + s]);
    __syncthreads();
  }
  const float bm = red[0];
  __syncthreads();

  float sum = 0.f;
  for (int t = tid; t < TT; t += 256) sum += __expf(score[b * TT + t] - bm);
  red[tid] = sum;
  __syncthreads();
  for (int s = 128; s > 0; s >>= 1) {
    if (tid < s) red[tid] += red[tid + s];
    __syncthreads();
  }
  const float inv = 1.f / red[0];
  __syncthreads();

  for (int t = tid; t < TT; t += 256)
    attn[b * TT + t] = __expf(score[b * TT + t] - bm) * inv;
}

// ---------------------------------------------------------------------------
// K4: context[b,d] = sum_t attn[b,t] * values[b,t,d]  (fp32, float4)
// ---------------------------------------------------------------------------
#define SPLIT 16
__global__ __launch_bounds__(256) void context_kernel(
    const float* __restrict__ values, const float* __restrict__ attn,
    float* __restrict__ ctx) {
  const int b = blockIdx.y;
  const int t0 = blockIdx.x * (TT / SPLIT);
  const int d = (threadIdx.x & 127) * 4;
  const int rg = threadIdx.x >> 7;
  float4 a = {0.f, 0.f, 0.f, 0.f};
  for (int t = t0 + rg; t < t0 + TT / SPLIT; t += 2) {
    const float w = attn[b * TT + t];
    const float4 v = *(const float4*)(values + (size_t)(b * TT + t) * DD + d);
    a.x += w * v.x; a.y += w * v.y; a.z += w * v.z; a.w += w * v.w;
  }
  atomicAdd(&ctx[b * DD + d + 0], a.x);
  atomicAdd(&ctx[b * DD + d + 1], a.y);
  atomicAdd(&ctx[b * DD + d + 2], a.z);
  atomicAdd(&ctx[b * DD + d + 3], a.w);
}

// ---------------------------------------------------------------------------
extern "C" void kernel_launch(void* const* d_in, const int* in_sizes, int n_in,
                              void* d_out, int out_size, void* d_ws, size_t ws_size,
                              hipStream_t stream) {
  const float* query  = (const float*)d_in[0];
  const float* values = (const float*)d_in[1];
  const float* W1     = (const float*)d_in[2];
  const float* b1     = (const float*)d_in[3];
  const float* W2     = (const float*)d_in[4];
  const float* b2     = (const float*)d_in[5];
  const float* V      = (const float*)d_in[6];
  // d_in[7] = bV: uniform score shift -> softmax-invariant, dropped.

  float* ctx  = (float*)d_out;             // [B,D]
  float* attn = (float*)d_out + BB * DD;   // [B,T,1]

  // ws: qb 64KB | score 256KB | w1a 512KB
  float* qb           = (float*)d_ws;                        // [B,U] fp32
  float* score        = qb + BB * UU;                        // [B*T] fp32
  unsigned short* w1a = (unsigned short*)(score + BB * TT);  // 512KB blocked bf16

  hipMemsetAsync(ctx, 0, BB * DD * sizeof(float), stream);  // context atomics

  pack_w1a_kernel<<<16, 256, 0, stream>>>(W1, w1a);
  projq_kernel<<<dim3(BB, UU / 256), 256, 0, stream>>>(query, W2, b2, b1, qb);

  score_kernel<<<(BB * TT) / SBM, 512, 0, stream>>>(values, w1a, qb, V, score);

  softmax_kernel<<<BB, 256, 0, stream>>>(score, attn);

  context_kernel<<<dim3(SPLIT, BB), 256, 0, stream>>>(values, attn, ctx);
}

// Round 10
// 101.140 us; speedup vs baseline: 1.6405x; 1.1075x over previous
//
#include <hip/hip_runtime.h>
#include <hip/hip_bf16.h>
#include <math.h>

// BahdanauAttention: B=32, T=2048, D=512, U=512, fp32 in/out.
#define BB 32
#define TT 2048
#define DD 512
#define UU 512

typedef __attribute__((ext_vector_type(8))) short short8v;     // MFMA bf16 A/B frag
typedef __attribute__((ext_vector_type(4))) float floatx4;     // MFMA C/D frag
typedef __attribute__((ext_vector_type(8))) unsigned short ushort8v;
typedef __attribute__((ext_vector_type(4))) unsigned short ushort4v;

static __device__ inline unsigned short f2bf(float f) {
  __hip_bfloat16 h = __float2bfloat16(f);
  return *reinterpret_cast<unsigned short*>(&h);
}

static __device__ inline float fast_tanh(float x) {
  x = fminf(fmaxf(x, -15.f), 15.f);
  float e2 = __expf(2.f * x);
  return (e2 - 1.f) * __builtin_amdgcn_rcpf(e2 + 1.f);
}

// ---------------------------------------------------------------------------
// K0: W1[k][u] fp32 -> w1a blocked bf16 [kt(16)][kg(4)][u(512)][8]:
// chunk (kt,kg,u)[e] = bf16(W1[kt*32+kg*8+e][u]).
// grid (16 kt, 4 uc), block 256: each block does a 32k x 128u tile.
// ---------------------------------------------------------------------------
__global__ __launch_bounds__(256) void pack_w1a_kernel(
    const float* __restrict__ W1, unsigned short* __restrict__ w1a) {
  __shared__ float Wf[32][132];  // pitch 132 -> col-gather conflict-free
  const int kt = blockIdx.x, uc = blockIdx.y;
  const int tid = threadIdx.x;
  {
    const int k = tid >> 3;
    const int u16 = (tid & 7) * 16;
    const float* src = W1 + (size_t)(kt * 32 + k) * UU + uc * 128 + u16;
    #pragma unroll
    for (int q = 0; q < 4; ++q) {
      const float4 v = *(const float4*)(src + q * 4);
      Wf[k][u16 + q * 4 + 0] = v.x;
      Wf[k][u16 + q * 4 + 1] = v.y;
      Wf[k][u16 + q * 4 + 2] = v.z;
      Wf[k][u16 + q * 4 + 3] = v.w;
    }
  }
  __syncthreads();
  unsigned short* dst = w1a + (size_t)kt * 16384;  // 32 KB per kt
  #pragma unroll
  for (int s = 0; s < 2; ++s) {
    const int c = s * 256 + tid;           // local chunk 0..511
    const int kg = c >> 7;
    const int u = c & 127;
    ushort8v o;
    #pragma unroll
    for (int e = 0; e < 8; ++e) o[e] = f2bf(Wf[kg * 8 + e][u]);
    *(ushort8v*)(dst + ((size_t)kg * 512 + uc * 128 + u) * 8) = o;
  }
}

// ---------------------------------------------------------------------------
// K1: qb[b,u] = query[b,:] @ W2[:,u] + b2[u] + b1[u]
// ---------------------------------------------------------------------------
__global__ __launch_bounds__(256) void projq_kernel(
    const float* __restrict__ query, const float* __restrict__ W2,
    const float* __restrict__ b2, const float* __restrict__ b1,
    float* __restrict__ qb) {
  int b = blockIdx.x;
  int u = blockIdx.y * 256 + threadIdx.x;
  float acc = b2[u] + b1[u];
  const float* q = query + b * DD;
  #pragma unroll 16
  for (int d = 0; d < DD; ++d) acc += q[d] * W2[(size_t)d * UU + u];
  qb[b * UU + u] = acc;
}

// ---------------------------------------------------------------------------
// K2: swapped-operand MFMA score kernel, 2-deep B pipeline (race-free class:
// plain loads + full-drain __syncthreads only).
// A = W1 (per-wave-private): direct global->VGPR from L2-hot w1a, reg dbuf.
// B = values rows (HBM, read once): br[2] 2-deep reg prefetch; ds_write of
// B(t+1) uses a value loaded a FULL iteration earlier -> HBM latency hidden.
// One barrier per K-step. 8 waves; wave = 64u x 64m. LDS ~14 KB.
// ---------------------------------------------------------------------------
#define SBM 64

__global__ __launch_bounds__(512, 4) void score_kernel(
    const float* __restrict__ values, const unsigned short* __restrict__ w1a,
    const float* __restrict__ qb, const float* __restrict__ V,
    float* __restrict__ score) {
  __shared__ __align__(16) unsigned short Bs[2][4][SBM][8];  // 2 x 4 KB [kg][m][8]
  __shared__ float qv_lds[512];
  __shared__ float vv_lds[512];
  __shared__ float part[8][SBM];

  const int tid = threadIdx.x;
  const int row0 = blockIdx.x * SBM;
  const int b = row0 >> 11;           // row0 / TT
  const int lane = tid & 63;
  const int wid = tid >> 6;           // 8 waves -> u slice
  const int wu = wid * 64;
  const int fr = lane & 15;
  const int kg = lane >> 4;

  qv_lds[tid] = qb[b * UU + tid];     // b1,b2 folded into qb
  vv_lds[tid] = V[tid];

  // B staging coords: thread -> (row sm, k-quad sj)
  const int sm = tid >> 3;
  const int sj = tid & 7;
  const float* bsrc = values + (size_t)(row0 + sm) * DD + sj * 4;
  const int bofs = (sj >> 1) * (SBM * 8) + sm * 8 + (sj & 1) * 4;  // ushort ofs

  // A-frag per-lane chunk offset (ushorts)
  const size_t aofs = (size_t)(kg * 512 + wu + fr) * 8;

  floatx4 acc[4][4] = {};  // [ju][jm]
  short8v af[2][4];
  float4 br[2];

  // ---- prologue: B(0)->slot0, A(0) frags, write B(0), B(1)->slot1 ----
  br[0] = *(const float4*)(bsrc);
  #pragma unroll
  for (int ju = 0; ju < 4; ++ju)
    af[0][ju] = *(const short8v*)(w1a + aofs + (size_t)ju * 128);
  {
    ushort4v q4 = {f2bf(br[0].x), f2bf(br[0].y), f2bf(br[0].z), f2bf(br[0].w)};
    *(ushort4v*)((unsigned short*)&Bs[0][0][0][0] + bofs) = q4;
  }
  br[1] = *(const float4*)(bsrc + 32);
  __syncthreads();

  // ---- main loop: one barrier per K-step; all indices static under unroll ----
  #pragma unroll
  for (int t = 0; t < 16; ++t) {
    const int cur = t & 1;
    const int nxt = cur ^ 1;

    // issue next-next B (slot t&1 is free: B(t) already in LDS)
    if (t + 2 < 16)
      br[t & 1] = *(const float4*)(bsrc + (size_t)(t + 2) * 32);
    // issue next A frags (L2)
    if (t + 1 < 16) {
      #pragma unroll
      for (int ju = 0; ju < 4; ++ju)
        af[nxt][ju] = *(const short8v*)(w1a + (size_t)(t + 1) * 16384 + aofs + (size_t)ju * 128);
    }

    // ---- compute current: 16 MFMA/wave ----
    #pragma unroll
    for (int jm = 0; jm < 4; ++jm) {
      const short8v bfv = *(const short8v*)&Bs[cur][kg][jm * 16 + fr][0];
      #pragma unroll
      for (int ju = 0; ju < 4; ++ju)
        acc[ju][jm] = __builtin_amdgcn_mfma_f32_16x16x32_bf16(af[cur][ju], bfv, acc[ju][jm], 0, 0, 0);
    }

    // ---- late-write B(t+1): value is a full iteration old (latency hidden) ----
    if (t + 1 < 16) {
      const float4 bb = br[(t + 1) & 1];
      ushort4v q4 = {f2bf(bb.x), f2bf(bb.y), f2bf(bb.z), f2bf(bb.w)};
      *(ushort4v*)((unsigned short*)&Bs[nxt][0][0][0] + bofs) = q4;
      __syncthreads();
    }
  }

  // ---- epilogue: tanh + V-weight; u on the register axis ----
  // C[u][m]: m = jm*16 + fr, u = wu + ju*16 + kg*4 + reg
  float pm[4] = {0.f, 0.f, 0.f, 0.f};
  #pragma unroll
  for (int ju = 0; ju < 4; ++ju) {
    const float4 qv = *(const float4*)&qv_lds[wu + ju * 16 + kg * 4];
    const float4 vv = *(const float4*)&vv_lds[wu + ju * 16 + kg * 4];
    const float qa[4] = {qv.x, qv.y, qv.z, qv.w};
    const float va[4] = {vv.x, vv.y, vv.z, vv.w};
    #pragma unroll
    for (int jm = 0; jm < 4; ++jm)
      #pragma unroll
      for (int reg = 0; reg < 4; ++reg)
        pm[jm] += fast_tanh(acc[ju][jm][reg] + qa[reg]) * va[reg];
  }
  #pragma unroll
  for (int jm = 0; jm < 4; ++jm) {
    pm[jm] += __shfl_xor(pm[jm], 16, 64);
    pm[jm] += __shfl_xor(pm[jm], 32, 64);
  }
  if (lane < 16) {
    #pragma unroll
    for (int jm = 0; jm < 4; ++jm) part[wid][jm * 16 + lane] = pm[jm];
  }
  __syncthreads();
  if (tid < SBM) {
    float s = 0.f;
    #pragma unroll
    for (int w = 0; w < 8; ++w) s += part[w][tid];
    score[row0 + tid] = s;
  }
}

// ---------------------------------------------------------------------------
// K3: softmax over T per batch.
// ---------------------------------------------------------------------------
__global__ __launch_bounds__(256) void softmax_kernel(
    const float* __restrict__ score, float* __restrict__ attn) {
  const int b = blockIdx.x;
  const int tid = threadIdx.x;
  __shared__ float red[256];

  float m = -INFINITY;
  for (int t = tid; t < TT; t += 256) m = fmaxf(m, score[b * TT + t]);
  red[tid] = m;
  __syncthreads();
  for (int s = 128; s > 0; s >>= 1) {
    if (tid < s) red[tid] = fmaxf(red[tid], red[tid + s]);
    __syncthreads();
  }
  const float bm = red[0];
  __syncthreads();

  float sum = 0.f;
  for (int t = tid; t < TT; t += 256) sum += __expf(score[b * TT + t] - bm);
  red[tid] = sum;
  __syncthreads();
  for (int s = 128; s > 0; s >>= 1) {
    if (tid < s) red[tid] += red[tid + s];
    __syncthreads();
  }
  const float inv = 1.f / red[0];
  __syncthreads();

  for (int t = tid; t < TT; t += 256)
    attn[b * TT + t] = __expf(score[b * TT + t] - bm) * inv;
}

// ---------------------------------------------------------------------------
// K4a: context partials, NO atomics. grid (64 splits, 32 b), block 128.
// partial[s][b][d] = sum over 32 t's of attn*values. 2048 blocks -> high TLP.
// ---------------------------------------------------------------------------
#define CSPLIT 64
__global__ __launch_bounds__(128) void context1_kernel(
    const float* __restrict__ values, const float* __restrict__ attn,
    float* __restrict__ partial) {
  const int s = blockIdx.x;
  const int b = blockIdx.y;
  const int t0 = s * (TT / CSPLIT);
  const int d = threadIdx.x * 4;
  float4 a = {0.f, 0.f, 0.f, 0.f};
  #pragma unroll 4
  for (int t = t0; t < t0 + TT / CSPLIT; ++t) {
    const float w = attn[b * TT + t];
    const float4 v = *(const float4*)(values + (size_t)(b * TT + t) * DD + d);
    a.x += w * v.x; a.y += w * v.y; a.z += w * v.z; a.w += w * v.w;
  }
  *(float4*)(partial + ((size_t)s * BB + b) * DD + d) = a;
}

// ---------------------------------------------------------------------------
// K4b: reduce partials -> ctx. grid (32 b), block 128 (one float4 d-slot each).
// ---------------------------------------------------------------------------
__global__ __launch_bounds__(128) void context2_kernel(
    const float* __restrict__ partial, float* __restrict__ ctx) {
  const int b = blockIdx.x;
  const int d = threadIdx.x * 4;
  float4 a = {0.f, 0.f, 0.f, 0.f};
  #pragma unroll 8
  for (int s = 0; s < CSPLIT; ++s) {
    const float4 p = *(const float4*)(partial + ((size_t)s * BB + b) * DD + d);
    a.x += p.x; a.y += p.y; a.z += p.z; a.w += p.w;
  }
  *(float4*)(ctx + (size_t)b * DD + d) = a;
}

// ---------------------------------------------------------------------------
extern "C" void kernel_launch(void* const* d_in, const int* in_sizes, int n_in,
                              void* d_out, int out_size, void* d_ws, size_t ws_size,
                              hipStream_t stream) {
  const float* query  = (const float*)d_in[0];
  const float* values = (const float*)d_in[1];
  const float* W1     = (const float*)d_in[2];
  const float* b1     = (const float*)d_in[3];
  const float* W2     = (const float*)d_in[4];
  const float* b2     = (const float*)d_in[5];
  const float* V      = (const float*)d_in[6];
  // d_in[7] = bV: uniform score shift -> softmax-invariant, dropped.

  float* ctx  = (float*)d_out;             // [B,D]
  float* attn = (float*)d_out + BB * DD;   // [B,T,1]

  // ws: qb 64KB | score 256KB | w1a 512KB | partial 4MB
  float* qb           = (float*)d_ws;                        // [B,U] fp32
  float* score        = qb + BB * UU;                        // [B*T] fp32
  unsigned short* w1a = (unsigned short*)(score + BB * TT);  // 512KB blocked bf16
  float* partial      = (float*)(w1a + (size_t)UU * DD);     // [64][B][D] fp32

  pack_w1a_kernel<<<dim3(16, 4), 256, 0, stream>>>(W1, w1a);
  projq_kernel<<<dim3(BB, UU / 256), 256, 0, stream>>>(query, W2, b2, b1, qb);

  score_kernel<<<(BB * TT) / SBM, 512, 0, stream>>>(values, w1a, qb, V, score);

  softmax_kernel<<<BB, 256, 0, stream>>>(score, attn);

  context1_kernel<<<dim3(CSPLIT, BB), 128, 0, stream>>>(values, attn, partial);
  context2_kernel<<<BB, 128, 0, stream>>>(partial, ctx);
}

// Round 11
// 99.633 us; speedup vs baseline: 1.6653x; 1.0151x over previous
//
#include <hip/hip_runtime.h>
#include <hip/hip_bf16.h>
#include <math.h>

// BahdanauAttention: B=32, T=2048, D=512, U=512, fp32 in/out.
#define BB 32
#define TT 2048
#define DD 512
#define UU 512

typedef __attribute__((ext_vector_type(8))) short short8v;     // MFMA bf16 A/B frag
typedef __attribute__((ext_vector_type(4))) float floatx4;     // MFMA C/D frag
typedef __attribute__((ext_vector_type(8))) unsigned short ushort8v;
typedef __attribute__((ext_vector_type(4))) unsigned short ushort4v;

static __device__ inline unsigned short f2bf(float f) {
  __hip_bfloat16 h = __float2bfloat16(f);
  return *reinterpret_cast<unsigned short*>(&h);
}

static __device__ inline float fast_tanh(float x) {
  x = fminf(fmaxf(x, -15.f), 15.f);
  float e2 = __expf(2.f * x);
  return (e2 - 1.f) * __builtin_amdgcn_rcpf(e2 + 1.f);
}

// ---------------------------------------------------------------------------
// K0: W1[k][u] fp32 -> w1a blocked bf16 [kt(16)][kg(4)][u(512)][8]:
// chunk (kt,kg,u)[e] = bf16(W1[kt*32+kg*8+e][u]).
// grid (16 kt, 4 uc), block 256.
// ---------------------------------------------------------------------------
__global__ __launch_bounds__(256) void pack_w1a_kernel(
    const float* __restrict__ W1, unsigned short* __restrict__ w1a) {
  __shared__ float Wf[32][132];  // pitch 132 -> col-gather conflict-free
  const int kt = blockIdx.x, uc = blockIdx.y;
  const int tid = threadIdx.x;
  {
    const int k = tid >> 3;
    const int u16 = (tid & 7) * 16;
    const float* src = W1 + (size_t)(kt * 32 + k) * UU + uc * 128 + u16;
    #pragma unroll
    for (int q = 0; q < 4; ++q) {
      const float4 v = *(const float4*)(src + q * 4);
      Wf[k][u16 + q * 4 + 0] = v.x;
      Wf[k][u16 + q * 4 + 1] = v.y;
      Wf[k][u16 + q * 4 + 2] = v.z;
      Wf[k][u16 + q * 4 + 3] = v.w;
    }
  }
  __syncthreads();
  unsigned short* dst = w1a + (size_t)kt * 16384;  // 32 KB per kt
  #pragma unroll
  for (int s = 0; s < 2; ++s) {
    const int c = s * 256 + tid;           // local chunk 0..511
    const int kg = c >> 7;
    const int u = c & 127;
    ushort8v o;
    #pragma unroll
    for (int e = 0; e < 8; ++e) o[e] = f2bf(Wf[kg * 8 + e][u]);
    *(ushort8v*)(dst + ((size_t)kg * 512 + uc * 128 + u) * 8) = o;
  }
}

// ---------------------------------------------------------------------------
// K1: qb[b,u] = query[b,:] @ W2[:,u] + b2[u] + b1[u]
// ---------------------------------------------------------------------------
__global__ __launch_bounds__(256) void projq_kernel(
    const float* __restrict__ query, const float* __restrict__ W2,
    const float* __restrict__ b2, const float* __restrict__ b1,
    float* __restrict__ qb) {
  int b = blockIdx.x;
  int u = blockIdx.y * 256 + threadIdx.x;
  float acc = b2[u] + b1[u];
  const float* q = query + b * DD;
  #pragma unroll 16
  for (int d = 0; d < DD; ++d) acc += q[d] * W2[(size_t)d * UU + u];
  qb[b * UU + u] = acc;
}

// ---------------------------------------------------------------------------
// K2: swapped-operand MFMA score kernel — FULL-PANEL B staging, barrier-free
// K-loop. The per-block B panel (64 rows x 512 k bf16) is only 64 KB: stage
// it ONCE (deep-MLP fp32 loads + cvt), one __syncthreads, then 16 K-steps
// with no barriers. A-frags (per-wave-private W1 slice) stream from L2-hot
// w1a with register double-buffering — nothing drains them now.
// 8 waves; wave = 64u x 64m. LDS ~70 KB -> 2 blocks/CU.
// ---------------------------------------------------------------------------
#define SBM 64

__global__ __launch_bounds__(512, 4) void score_kernel(
    const float* __restrict__ values, const unsigned short* __restrict__ w1a,
    const float* __restrict__ qb, const float* __restrict__ V,
    float* __restrict__ score) {
  __shared__ __align__(16) unsigned short Bp[16][4][SBM][8];  // 64 KB [kt][kg][m][8]
  __shared__ float qv_lds[512];
  __shared__ float vv_lds[512];
  __shared__ float part[8][SBM];

  const int tid = threadIdx.x;
  const int row0 = blockIdx.x * SBM;
  const int b = row0 >> 11;           // row0 / TT
  const int lane = tid & 63;
  const int wid = tid >> 6;           // 8 waves -> u slice
  const int wu = wid * 64;
  const int fr = lane & 15;
  const int kg = lane >> 4;

  qv_lds[tid] = qb[b * UU + tid];     // b1,b2 folded into qb
  vv_lds[tid] = V[tid];

  // ---- stage the WHOLE B panel once: thread owns (row sm, k-quad sj) ----
  // For kt: load values[row0+sm][kt*32 + sj*4 ..+4], cvt, write
  // Bp[kt][sj>>1][sm][(sj&1)*4]. Two batches of 8 for MLP within VGPR budget.
  const int sm = tid >> 3;
  const int sj = tid & 7;
  const float* bsrc = values + (size_t)(row0 + sm) * DD + sj * 4;
  unsigned short* bdst = &Bp[0][sj >> 1][sm][(sj & 1) * 4];
  #pragma unroll
  for (int half = 0; half < 2; ++half) {
    float4 r[8];
    #pragma unroll
    for (int q = 0; q < 8; ++q)
      r[q] = *(const float4*)(bsrc + (size_t)(half * 8 + q) * 32);
    #pragma unroll
    for (int q = 0; q < 8; ++q) {
      ushort4v o = {f2bf(r[q].x), f2bf(r[q].y), f2bf(r[q].z), f2bf(r[q].w)};
      *(ushort4v*)(bdst + (size_t)(half * 8 + q) * 2048) = o;  // kt stride = 2048 ushorts
    }
  }
  __syncthreads();  // the ONLY pre-epilogue barrier

  // ---- barrier-free K-loop: A reg-dbuf from L2, B from LDS (read-only) ----
  const size_t aofs = (size_t)(kg * 512 + wu + fr) * 8;
  floatx4 acc[4][4] = {};  // [ju][jm]
  short8v af[2][4];
  #pragma unroll
  for (int ju = 0; ju < 4; ++ju)
    af[0][ju] = *(const short8v*)(w1a + aofs + (size_t)ju * 128);

  #pragma unroll
  for (int t = 0; t < 16; ++t) {
    const int cur = t & 1;
    const int nxt = cur ^ 1;
    if (t + 1 < 16) {  // prefetch next A frags (L2-hot, per-wave-private)
      #pragma unroll
      for (int ju = 0; ju < 4; ++ju)
        af[nxt][ju] = *(const short8v*)(w1a + (size_t)(t + 1) * 16384 + aofs + (size_t)ju * 128);
    }
    #pragma unroll
    for (int jm = 0; jm < 4; ++jm) {
      const short8v bfv = *(const short8v*)&Bp[t][kg][jm * 16 + fr][0];
      #pragma unroll
      for (int ju = 0; ju < 4; ++ju)
        acc[ju][jm] = __builtin_amdgcn_mfma_f32_16x16x32_bf16(af[cur][ju], bfv, acc[ju][jm], 0, 0, 0);
    }
  }

  // ---- epilogue: tanh + V-weight; u on the register axis ----
  // C[u][m]: m = jm*16 + fr, u = wu + ju*16 + kg*4 + reg
  float pm[4] = {0.f, 0.f, 0.f, 0.f};
  #pragma unroll
  for (int ju = 0; ju < 4; ++ju) {
    const float4 qv = *(const float4*)&qv_lds[wu + ju * 16 + kg * 4];
    const float4 vv = *(const float4*)&vv_lds[wu + ju * 16 + kg * 4];
    const float qa[4] = {qv.x, qv.y, qv.z, qv.w};
    const float va[4] = {vv.x, vv.y, vv.z, vv.w};
    #pragma unroll
    for (int jm = 0; jm < 4; ++jm)
      #pragma unroll
      for (int reg = 0; reg < 4; ++reg)
        pm[jm] += fast_tanh(acc[ju][jm][reg] + qa[reg]) * va[reg];
  }
  #pragma unroll
  for (int jm = 0; jm < 4; ++jm) {
    pm[jm] += __shfl_xor(pm[jm], 16, 64);
    pm[jm] += __shfl_xor(pm[jm], 32, 64);
  }
  if (lane < 16) {
    #pragma unroll
    for (int jm = 0; jm < 4; ++jm) part[wid][jm * 16 + lane] = pm[jm];
  }
  __syncthreads();
  if (tid < SBM) {
    float s = 0.f;
    #pragma unroll
    for (int w = 0; w < 8; ++w) s += part[w][tid];
    score[row0 + tid] = s;
  }
}

// ---------------------------------------------------------------------------
// K3: softmax over T per batch.
// ---------------------------------------------------------------------------
__global__ __launch_bounds__(256) void softmax_kernel(
    const float* __restrict__ score, float* __restrict__ attn) {
  const int b = blockIdx.x;
  const int tid = threadIdx.x;
  __shared__ float red[256];

  float m = -INFINITY;
  for (int t = tid; t < TT; t += 256) m = fmaxf(m, score[b * TT + t]);
  red[tid] = m;
  __syncthreads();
  for (int s = 128; s > 0; s >>= 1) {
    if (tid < s) red[tid] = fmaxf(red[tid], red[tid + s]);
    __syncthreads();
  }
  const float bm = red[0];
  __syncthreads();

  float sum = 0.f;
  for (int t = tid; t < TT; t += 256) sum += __expf(score[b * TT + t] - bm);
  red[tid] = sum;
  __syncthreads();
  for (int s = 128; s > 0; s >>= 1) {
    if (tid < s) red[tid] += red[tid + s];
    __syncthreads();
  }
  const float inv = 1.f / red[0];
  __syncthreads();

  for (int t = tid; t < TT; t += 256)
    attn[b * TT + t] = __expf(score[b * TT + t] - bm) * inv;
}

// ---------------------------------------------------------------------------
// K4a: context partials, NO atomics. grid (64 splits, 32 b), block 128.
// ---------------------------------------------------------------------------
#define CSPLIT 64
__global__ __launch_bounds__(128) void context1_kernel(
    const float* __restrict__ values, const float* __restrict__ attn,
    float* __restrict__ partial) {
  const int s = blockIdx.x;
  const int b = blockIdx.y;
  const int t0 = s * (TT / CSPLIT);
  const int d = threadIdx.x * 4;
  float4 a = {0.f, 0.f, 0.f, 0.f};
  #pragma unroll 4
  for (int t = t0; t < t0 + TT / CSPLIT; ++t) {
    const float w = attn[b * TT + t];
    const float4 v = *(const float4*)(values + (size_t)(b * TT + t) * DD + d);
    a.x += w * v.x; a.y += w * v.y; a.z += w * v.z; a.w += w * v.w;
  }
  *(float4*)(partial + ((size_t)s * BB + b) * DD + d) = a;
}

// ---------------------------------------------------------------------------
// K4b: reduce partials -> ctx. grid (32 b), block 128.
// ---------------------------------------------------------------------------
__global__ __launch_bounds__(128) void context2_kernel(
    const float* __restrict__ partial, float* __restrict__ ctx) {
  const int b = blockIdx.x;
  const int d = threadIdx.x * 4;
  float4 a = {0.f, 0.f, 0.f, 0.f};
  #pragma unroll 8
  for (int s = 0; s < CSPLIT; ++s) {
    const float4 p = *(const float4*)(partial + ((size_t)s * BB + b) * DD + d);
    a.x += p.x; a.y += p.y; a.z += p.z; a.w += p.w;
  }
  *(float4*)(ctx + (size_t)b * DD + d) = a;
}

// ---------------------------------------------------------------------------
extern "C" void kernel_launch(void* const* d_in, const int* in_sizes, int n_in,
                              void* d_out, int out_size, void* d_ws, size_t ws_size,
                              hipStream_t stream) {
  const float* query  = (const float*)d_in[0];
  const float* values = (const float*)d_in[1];
  const float* W1     = (const float*)d_in[2];
  const float* b1     = (const float*)d_in[3];
  const float* W2     = (const float*)d_in[4];
  const float* b2     = (const float*)d_in[5];
  const float* V      = (const float*)d_in[6];
  // d_in[7] = bV: uniform score shift -> softmax-invariant, dropped.

  float* ctx  = (float*)d_out;             // [B,D]
  float* attn = (float*)d_out + BB * DD;   // [B,T,1]

  // ws: qb 64KB | score 256KB | w1a 512KB | partial 4MB
  float* qb           = (float*)d_ws;                        // [B,U] fp32
  float* score        = qb + BB * UU;                        // [B*T] fp32
  unsigned short* w1a = (unsigned short*)(score + BB * TT);  // 512KB blocked bf16
  float* partial      = (float*)(w1a + (size_t)UU * DD);     // [64][B][D] fp32

  pack_w1a_kernel<<<dim3(16, 4), 256, 0, stream>>>(W1, w1a);
  projq_kernel<<<dim3(BB, UU / 256), 256, 0, stream>>>(query, W2, b2, b1, qb);

  score_kernel<<<(BB * TT) / SBM, 512, 0, stream>>>(values, w1a, qb, V, score);

  softmax_kernel<<<BB, 256, 0, stream>>>(score, attn);

  context1_kernel<<<dim3(CSPLIT, BB), 128, 0, stream>>>(values, attn, partial);
  context2_kernel<<<BB, 128, 0, stream>>>(partial, ctx);
}